// Round 1
// baseline (276.536 us; speedup 1.0000x reference)
//
#include <hip/hip_runtime.h>

typedef _Float16 f16x8 __attribute__((ext_vector_type(8)));
typedef float f32x4 __attribute__((ext_vector_type(4)));

#define N_IMP 300000

__device__ __forceinline__ unsigned short f2h(float f) {
  _Float16 h = (_Float16)f;  // v_cvt_f16_f32, RNE
  return __builtin_bit_cast(unsigned short, h);
}

// Packed f16 weights in d_ws (ushort units):
//  [0,16384)      Wa  [n][k]  = W1[0:128] + W1[256:384] + W1[384:512]
//  [16384,32768)  Wb  [n][k]  = 3*W1[128:256]
//  [32768,49152)  W2p [n][k]
//  [49152,65536)  W3p [n][k]
//  [65536,67584)  Wop [16][128] (cols 6..15 zero)
__global__ __launch_bounds__(256) void prep_kernel(
    const float* __restrict__ W1, const float* __restrict__ W2,
    const float* __restrict__ W3, const float* __restrict__ Wo,
    unsigned short* __restrict__ P) {
  int t = blockIdx.x * 256 + threadIdx.x;  // grid sized exactly: 264*256 = 67584
  float v;
  if (t < 16384) {
    int n = t >> 7, k = t & 127;
    v = W1[k * 128 + n] + W1[(k + 256) * 128 + n] + W1[(k + 384) * 128 + n];
  } else if (t < 32768) {
    int i = t - 16384; int n = i >> 7, k = i & 127;
    v = 3.0f * W1[(k + 128) * 128 + n];
  } else if (t < 49152) {
    int i = t - 32768; int n = i >> 7, k = i & 127;
    v = W2[k * 128 + n];
  } else if (t < 65536) {
    int i = t - 49152; int n = i >> 7, k = i & 127;
    v = W3[k * 128 + n];
  } else {
    int i = t - 65536; int n = i >> 7, k = i & 127;
    v = (n < 6) ? Wo[k * 6 + n] : 0.0f;
  }
  P[t] = f2h(v);
}

// LDS activation tiles: [64 rows][128 k] f16, XOR-swizzled (G4: row-major D=128
// is a 16/32-way bank conflict on ds_read_b128 without it).
__device__ __forceinline__ int swz_off(int row, int kbyte) {
  return (row * 256 + kbyte) ^ ((row & 7) << 4);
}

__device__ __forceinline__ f16x8 lds_frag(const unsigned short* buf, int row, int k0) {
  return *(const f16x8*)((const char*)buf + swz_off(row, k0 * 2));
}

__device__ __forceinline__ void lds_st4(unsigned short* buf, int row, int k0,
                                        float a, float b, float c, float d) {
  uint2 u;
  u.x = (unsigned int)f2h(a) | ((unsigned int)f2h(b) << 16);
  u.y = (unsigned int)f2h(c) | ((unsigned int)f2h(d) << 16);
  *(uint2*)((char*)buf + swz_off(row, k0 * 2)) = u;
}

__device__ __forceinline__ void lds_st1(unsigned short* buf, int row, int col, unsigned short v) {
  *(unsigned short*)((char*)buf + swz_off(row, col * 2)) = v;
}

// One MLP layer for this wave: C strip = rows [wr*32, wr*32+32) x cols [wc*64, wc*64+64).
// A-frag: row = l&15 (+16 for m=1), k = (l>>4)*8 + j. B packed [n][k] -> contiguous 16B.
// C/D: col = l&15, row = (l>>4)*4 + r.
template <bool DUAL>
__device__ __forceinline__ void mlp_layer(
    const unsigned short* A1, const unsigned short* __restrict__ B1,
    const unsigned short* A2, const unsigned short* __restrict__ B2,
    const float* __restrict__ bias, unsigned short* Obuf, int lane, int wr, int wc) {
  f32x4 acc[2][4] = {};
#pragma unroll
  for (int ks = 0; ks < 4; ++ks) {
    int k0 = ks * 32 + (lane >> 4) * 8;
    f16x8 a0 = lds_frag(A1, wr * 32 + (lane & 15), k0);
    f16x8 a1 = lds_frag(A1, wr * 32 + 16 + (lane & 15), k0);
#pragma unroll
    for (int n = 0; n < 4; ++n) {
      int col = wc * 64 + n * 16 + (lane & 15);
      f16x8 b = *(const f16x8*)(B1 + col * 128 + k0);
      acc[0][n] = __builtin_amdgcn_mfma_f32_16x16x32_f16(a0, b, acc[0][n], 0, 0, 0);
      acc[1][n] = __builtin_amdgcn_mfma_f32_16x16x32_f16(a1, b, acc[1][n], 0, 0, 0);
    }
  }
  if constexpr (DUAL) {
#pragma unroll
    for (int ks = 0; ks < 4; ++ks) {
      int k0 = ks * 32 + (lane >> 4) * 8;
      f16x8 a0 = lds_frag(A2, wr * 32 + (lane & 15), k0);
      f16x8 a1 = lds_frag(A2, wr * 32 + 16 + (lane & 15), k0);
#pragma unroll
      for (int n = 0; n < 4; ++n) {
        int col = wc * 64 + n * 16 + (lane & 15);
        f16x8 b = *(const f16x8*)(B2 + col * 128 + k0);
        acc[0][n] = __builtin_amdgcn_mfma_f32_16x16x32_f16(a0, b, acc[0][n], 0, 0, 0);
        acc[1][n] = __builtin_amdgcn_mfma_f32_16x16x32_f16(a1, b, acc[1][n], 0, 0, 0);
      }
    }
  }
  // bias + ReLU epilogue, write back in A-layout for the next layer
#pragma unroll
  for (int n = 0; n < 4; ++n) {
    int col = wc * 64 + n * 16 + (lane & 15);
    float bn = bias[col];
#pragma unroll
    for (int m = 0; m < 2; ++m) {
#pragma unroll
      for (int r = 0; r < 4; ++r) {
        float v = fmaxf(acc[m][n][r] + bn, 0.0f);
        lds_st1(Obuf, wr * 32 + m * 16 + (lane >> 4) * 4 + r, col, f2h(v));
      }
    }
  }
}

__global__ __launch_bounds__(256) void janossy_kernel(
    const float* __restrict__ h, const int* __restrict__ idx0,
    const int* __restrict__ idx1, const int* __restrict__ idx2,
    const int* __restrict__ idx3, const float* __restrict__ b1,
    const float* __restrict__ b2, const float* __restrict__ b3,
    const float* __restrict__ bo, const unsigned short* __restrict__ P,
    float* __restrict__ out) {
  __shared__ __attribute__((aligned(16))) unsigned short sA[64 * 128];
  __shared__ __attribute__((aligned(16))) unsigned short tA[64 * 128];
  __shared__ __attribute__((aligned(16))) unsigned short xA[64 * 128];

  const int tid = threadIdx.x;
  const int lane = tid & 63;
  const int wid = tid >> 6;
  const int wr = wid & 1, wc = wid >> 1;
  const int blk = blockIdx.x;

  // ---- stage: s = h0+h2+h3, t = h1 (fp32 adds, then one f16 rounding) ----
  {
    int row = tid >> 2, q = tid & 3;  // 4 threads per improper row, 32 k each
    int rg = blk * 64 + row;
    if (rg < N_IMP) {
      const float4* p0 = (const float4*)h + (long)idx0[rg] * 32 + q * 8;
      const float4* p1 = (const float4*)h + (long)idx1[rg] * 32 + q * 8;
      const float4* p2 = (const float4*)h + (long)idx2[rg] * 32 + q * 8;
      const float4* p3 = (const float4*)h + (long)idx3[rg] * 32 + q * 8;
#pragma unroll
      for (int c = 0; c < 8; ++c) {
        float4 v0 = p0[c], v1 = p1[c], v2 = p2[c], v3 = p3[c];
        int k0 = q * 32 + c * 4;
        lds_st4(sA, row, k0, v0.x + v2.x + v3.x, v0.y + v2.y + v3.y,
                v0.z + v2.z + v3.z, v0.w + v2.w + v3.w);
        lds_st4(tA, row, k0, v1.x, v1.y, v1.z, v1.w);
      }
    } else {
#pragma unroll
      for (int c = 0; c < 8; ++c) {
        int k0 = q * 32 + c * 4;
        lds_st4(sA, row, k0, 0.f, 0.f, 0.f, 0.f);
        lds_st4(tA, row, k0, 0.f, 0.f, 0.f, 0.f);
      }
    }
  }
  __syncthreads();
  // layer1: xA = relu(s@Wa + t@Wb + b1)
  mlp_layer<true>(sA, P, tA, P + 16384, b1, xA, lane, wr, wc);
  __syncthreads();
  // layer2: sA = relu(xA@W2 + b2)
  mlp_layer<false>(xA, P + 32768, nullptr, nullptr, b2, sA, lane, wr, wc);
  __syncthreads();
  // layer3: tA = relu(sA@W3 + b3)
  mlp_layer<false>(sA, P + 49152, nullptr, nullptr, b3, tA, lane, wr, wc);
  __syncthreads();
  // head: out = tA@Wo + bo  (each wave owns 16 rows; only cols 0..5 are real)
  {
    f32x4 acc = {0.f, 0.f, 0.f, 0.f};
#pragma unroll
    for (int ks = 0; ks < 4; ++ks) {
      int k0 = ks * 32 + (lane >> 4) * 8;
      f16x8 a = lds_frag(tA, wid * 16 + (lane & 15), k0);
      f16x8 b = *(const f16x8*)(P + 65536 + (lane & 15) * 128 + k0);
      acc = __builtin_amdgcn_mfma_f32_16x16x32_f16(a, b, acc, 0, 0, 0);
    }
    int col = lane & 15;
    if (col < 6) {
      float bov = bo[col];
#pragma unroll
      for (int r = 0; r < 4; ++r) {
        int rg = blk * 64 + wid * 16 + (lane >> 4) * 4 + r;
        if (rg < N_IMP) out[rg * 6 + col] = acc[r] + bov;
      }
    }
  }
}

extern "C" void kernel_launch(void* const* d_in, const int* in_sizes, int n_in,
                              void* d_out, int out_size, void* d_ws, size_t ws_size,
                              hipStream_t stream) {
  const float* h   = (const float*)d_in[0];
  const int* idx0  = (const int*)d_in[1];
  const int* idx1  = (const int*)d_in[2];
  const int* idx2  = (const int*)d_in[3];
  const int* idx3  = (const int*)d_in[4];
  const float* W1  = (const float*)d_in[5];
  const float* b1  = (const float*)d_in[6];
  const float* W2  = (const float*)d_in[7];
  const float* b2  = (const float*)d_in[8];
  const float* W3  = (const float*)d_in[9];
  const float* b3  = (const float*)d_in[10];
  const float* Wo  = (const float*)d_in[11];
  const float* bo  = (const float*)d_in[12];
  float* out = (float*)d_out;
  unsigned short* P = (unsigned short*)d_ws;  // needs 135168 B

  prep_kernel<<<dim3(264), dim3(256), 0, stream>>>(W1, W2, W3, Wo, P);
  janossy_kernel<<<dim3((N_IMP + 63) / 64), dim3(256), 0, stream>>>(
      h, idx0, idx1, idx2, idx3, b1, b2, b3, bo, P, out);
}

// Round 2
// 266.931 us; speedup vs baseline: 1.0360x; 1.0360x over previous
//
#include <hip/hip_runtime.h>

typedef _Float16 f16x8 __attribute__((ext_vector_type(8)));
typedef float f32x4 __attribute__((ext_vector_type(4)));

#define N_IMP 300000
#define N_ATOMS 100000

__device__ __forceinline__ unsigned short f2h(float f) {
  _Float16 h = (_Float16)f;  // v_cvt_f16_f32, RNE
  return __builtin_bit_cast(unsigned short, h);
}
__device__ __forceinline__ unsigned int pk2(float a, float b) {
  return (unsigned int)f2h(a) | ((unsigned int)f2h(b) << 16);
}

// Packed f16 weights in d_ws (ushort units):
//  [0,16384)      Wa  [n][k]  = W1[0:128] + W1[256:384] + W1[384:512]
//  [16384,32768)  Wb  [n][k]  = 3*W1[128:256]        (Wa|Wb = Wab [256][128])
//  [32768,49152)  W2p [n][k]
//  [49152,65536)  W3p [n][k]
//  [65536,67584)  Wop [16][128] (cols 6..15 zero)
//  [67584, +25.6M) uv  [atom][256] f16: u = h@Wa (0:128), v = h@Wb (128:256)
#define UV_OFF 67584
#define WS_NEED (2ull * (UV_OFF + (unsigned long long)N_ATOMS * 256))

__global__ __launch_bounds__(256) void prep_kernel(
    const float* __restrict__ W1, const float* __restrict__ W2,
    const float* __restrict__ W3, const float* __restrict__ Wo,
    unsigned short* __restrict__ P) {
  int t = blockIdx.x * 256 + threadIdx.x;  // grid sized exactly: 264*256 = 67584
  float v;
  if (t < 16384) {
    int n = t >> 7, k = t & 127;
    v = W1[k * 128 + n] + W1[(k + 256) * 128 + n] + W1[(k + 384) * 128 + n];
  } else if (t < 32768) {
    int i = t - 16384; int n = i >> 7, k = i & 127;
    v = 3.0f * W1[(k + 128) * 128 + n];
  } else if (t < 49152) {
    int i = t - 32768; int n = i >> 7, k = i & 127;
    v = W2[k * 128 + n];
  } else if (t < 65536) {
    int i = t - 49152; int n = i >> 7, k = i & 127;
    v = W3[k * 128 + n];
  } else {
    int i = t - 65536; int n = i >> 7, k = i & 127;
    v = (n < 6) ? Wo[k * 6 + n] : 0.0f;
  }
  P[t] = f2h(v);
}

// Swizzled LDS tiles, row stride 256 B (G4: row-major D=128 f16 is a 16-way
// conflict on ds_read_b128 without the XOR).
__device__ __forceinline__ int swz_off(int row, int kbyte) {
  return (row * 256 + kbyte) ^ ((row & 7) << 4);
}
__device__ __forceinline__ f16x8 lds_frag(const unsigned short* buf, int row, int k0) {
  return *(const f16x8*)((const char*)buf + swz_off(row, k0 * 2));
}
__device__ __forceinline__ void lds_st4(unsigned short* buf, int row, int k0,
                                        float a, float b, float c, float d) {
  uint2 u; u.x = pk2(a, b); u.y = pk2(c, d);
  *(uint2*)((char*)buf + swz_off(row, k0 * 2)) = u;
}
__device__ __forceinline__ void lds_st1(unsigned short* buf, int row, int col, unsigned short v) {
  *(unsigned short*)((char*)buf + swz_off(row, col * 2)) = v;
}
// Wave-local LDS fence: all lanes share one PC, so after this every ds_write
// issued by this wave is complete; "memory" clobber stops hipcc reordering the
// following ds_reads above it.
__device__ __forceinline__ void wave_lds_fence() {
  asm volatile("s_waitcnt lgkmcnt(0)" ::: "memory");
}

// ===================== new path: per-atom precompute =====================

// uv[atom][0:128] = h[atom]@Wa, uv[atom][128:256] = h[atom]@Wb, f16.
// Operand-swapped MFMA (D[feat][atom]) so each lane holds 4 CONSECUTIVE
// features of one atom -> 8 B packed stores (32 B contiguous per atom per
// store inst). A-frag = Wab[feat][k] (contiguous), B-frag = h-tile from LDS.
__global__ __launch_bounds__(256) void atom_gemm(
    const float* __restrict__ h, const unsigned short* __restrict__ P,
    unsigned short* __restrict__ uv) {
  __shared__ __attribute__((aligned(16))) unsigned short hT[4][16 * 128];
  const int lane = threadIdx.x & 63;
  const int wid = threadIdx.x >> 6;
  const int atom0 = blockIdx.x * 64 + wid * 16;

  {  // stage this wave's 16 atom rows (f32 -> f16, swizzled)
    int row = lane >> 2, q = lane & 3;
    int a = atom0 + row;
    if (a < N_ATOMS) {
      const float4* p = (const float4*)h + (long)a * 32 + q * 8;
#pragma unroll
      for (int c = 0; c < 8; ++c) {
        float4 v = p[c];
        lds_st4(hT[wid], row, q * 32 + c * 4, v.x, v.y, v.z, v.w);
      }
    } else {
#pragma unroll
      for (int c = 0; c < 8; ++c) lds_st4(hT[wid], row, q * 32 + c * 4, 0.f, 0.f, 0.f, 0.f);
    }
  }
  wave_lds_fence();

  f32x4 acc[16] = {};
#pragma unroll
  for (int ks = 0; ks < 4; ++ks) {
    int k0 = ks * 32 + (lane >> 4) * 8;
    f16x8 b = lds_frag(hT[wid], lane & 15, k0);  // B: col=atom, k contiguous
#pragma unroll
    for (int n = 0; n < 16; ++n) {
      f16x8 a = *(const f16x8*)(P + (n * 16 + (lane & 15)) * 128 + k0);  // A: row=feat
      acc[n] = __builtin_amdgcn_mfma_f32_16x16x32_f16(a, b, acc[n], 0, 0, 0);
    }
  }
  int a = atom0 + (lane & 15);
  if (a < N_ATOMS) {
    unsigned short* dst = uv + (long)a * 256 + (lane >> 4) * 4;
#pragma unroll
    for (int n = 0; n < 16; ++n) {
      uint2 w; w.x = pk2(acc[n][0], acc[n][1]); w.y = pk2(acc[n][2], acc[n][3]);
      *(uint2*)(dst + n * 16) = w;
    }
  }
}

// One hidden layer for one wave's private 16x128 tile: Y = relu(X @ B + bias).
__device__ __forceinline__ void wave_layer(
    const unsigned short* Xb, const unsigned short* __restrict__ B,
    const float* __restrict__ bias, unsigned short* Yb, int lane) {
  f32x4 acc[8] = {};
#pragma unroll
  for (int ks = 0; ks < 4; ++ks) {
    int k0 = ks * 32 + (lane >> 4) * 8;
    f16x8 a = lds_frag(Xb, lane & 15, k0);
#pragma unroll
    for (int n = 0; n < 8; ++n) {
      f16x8 b = *(const f16x8*)(B + (n * 16 + (lane & 15)) * 128 + k0);
      acc[n] = __builtin_amdgcn_mfma_f32_16x16x32_f16(a, b, acc[n], 0, 0, 0);
    }
  }
#pragma unroll
  for (int n = 0; n < 8; ++n) {
    int col = n * 16 + (lane & 15);
    float bn = bias[col];
#pragma unroll
    for (int r = 0; r < 4; ++r) {
      float v = fmaxf(acc[n][r] + bn, 0.0f);
      lds_st1(Yb, (lane >> 4) * 4 + r, col, f2h(v));
    }
  }
}

// Main: gather u0+u2+u3+v1 (+b1, relu) -> wave-private LDS tile -> L2,L3,head.
// NO __syncthreads anywhere: each wave owns 16 impropers end-to-end, only
// wave-local lgkmcnt fences between phases -> waves hide each other's gather
// latency instead of barrier-stalling on it.
__global__ __launch_bounds__(256) void janossy2(
    const unsigned short* __restrict__ uv, const int* __restrict__ idx0,
    const int* __restrict__ idx1, const int* __restrict__ idx2,
    const int* __restrict__ idx3, const float* __restrict__ b1,
    const float* __restrict__ b2, const float* __restrict__ b3,
    const float* __restrict__ bo, const unsigned short* __restrict__ P,
    float* __restrict__ out) {
  __shared__ __attribute__((aligned(16))) unsigned short X[4][16 * 128];
  __shared__ __attribute__((aligned(16))) unsigned short Y[4][16 * 128];
  const int lane = threadIdx.x & 63;
  const int wid = threadIdx.x >> 6;
  const int r0 = blockIdx.x * 64 + wid * 16;

  {  // gather phase: 4 lanes per improper row, 32 feats per lane
    int row = lane >> 2, q = lane & 3;
    int rg = r0 + row;
    if (rg < N_IMP) {
      long o0 = (long)idx0[rg] * 256;
      long o1 = (long)idx1[rg] * 256 + 128;
      long o2 = (long)idx2[rg] * 256;
      long o3 = (long)idx3[rg] * 256;
#pragma unroll
      for (int c = 0; c < 4; ++c) {
        int k0 = q * 32 + c * 8;
        f16x8 a0 = *(const f16x8*)(uv + o0 + k0);
        f16x8 a1 = *(const f16x8*)(uv + o1 + k0);
        f16x8 a2 = *(const f16x8*)(uv + o2 + k0);
        f16x8 a3 = *(const f16x8*)(uv + o3 + k0);
        float s[8];
#pragma unroll
        for (int j = 0; j < 8; ++j)
          s[j] = fmaxf((float)a0[j] + (float)a1[j] + (float)a2[j] + (float)a3[j]
                       + b1[k0 + j], 0.0f);
        uint4 w = {pk2(s[0], s[1]), pk2(s[2], s[3]), pk2(s[4], s[5]), pk2(s[6], s[7])};
        *(uint4*)((char*)X[wid] + swz_off(row, k0 * 2)) = w;
      }
    } else {
      uint4 z = {0, 0, 0, 0};
#pragma unroll
      for (int c = 0; c < 4; ++c)
        *(uint4*)((char*)X[wid] + swz_off(row, (q * 32 + c * 8) * 2)) = z;
    }
  }
  wave_lds_fence();
  wave_layer(X[wid], P + 32768, b2, Y[wid], lane);  // layer 2
  wave_lds_fence();
  wave_layer(Y[wid], P + 49152, b3, X[wid], lane);  // layer 3
  wave_lds_fence();
  {  // head: 16 rows x 6 cols
    f32x4 acc = {0.f, 0.f, 0.f, 0.f};
#pragma unroll
    for (int ks = 0; ks < 4; ++ks) {
      int k0 = ks * 32 + (lane >> 4) * 8;
      f16x8 a = lds_frag(X[wid], lane & 15, k0);
      f16x8 b = *(const f16x8*)(P + 65536 + (lane & 15) * 128 + k0);
      acc = __builtin_amdgcn_mfma_f32_16x16x32_f16(a, b, acc, 0, 0, 0);
    }
    int col = lane & 15;
    if (col < 6) {
      float bov = bo[col];
#pragma unroll
      for (int r = 0; r < 4; ++r) {
        int rg = r0 + (lane >> 4) * 4 + r;
        if (rg < N_IMP) out[rg * 6 + col] = acc[r] + bov;
      }
    }
  }
}

// ===================== fallback path (R1, needs only 135 KB ws) =====================

template <bool DUAL>
__device__ __forceinline__ void mlp_layer(
    const unsigned short* A1, const unsigned short* __restrict__ B1,
    const unsigned short* A2, const unsigned short* __restrict__ B2,
    const float* __restrict__ bias, unsigned short* Obuf, int lane, int wr, int wc) {
  f32x4 acc[2][4] = {};
#pragma unroll
  for (int ks = 0; ks < 4; ++ks) {
    int k0 = ks * 32 + (lane >> 4) * 8;
    f16x8 a0 = lds_frag(A1, wr * 32 + (lane & 15), k0);
    f16x8 a1 = lds_frag(A1, wr * 32 + 16 + (lane & 15), k0);
#pragma unroll
    for (int n = 0; n < 4; ++n) {
      int col = wc * 64 + n * 16 + (lane & 15);
      f16x8 b = *(const f16x8*)(B1 + col * 128 + k0);
      acc[0][n] = __builtin_amdgcn_mfma_f32_16x16x32_f16(a0, b, acc[0][n], 0, 0, 0);
      acc[1][n] = __builtin_amdgcn_mfma_f32_16x16x32_f16(a1, b, acc[1][n], 0, 0, 0);
    }
  }
  if constexpr (DUAL) {
#pragma unroll
    for (int ks = 0; ks < 4; ++ks) {
      int k0 = ks * 32 + (lane >> 4) * 8;
      f16x8 a0 = lds_frag(A2, wr * 32 + (lane & 15), k0);
      f16x8 a1 = lds_frag(A2, wr * 32 + 16 + (lane & 15), k0);
#pragma unroll
      for (int n = 0; n < 4; ++n) {
        int col = wc * 64 + n * 16 + (lane & 15);
        f16x8 b = *(const f16x8*)(B2 + col * 128 + k0);
        acc[0][n] = __builtin_amdgcn_mfma_f32_16x16x32_f16(a0, b, acc[0][n], 0, 0, 0);
        acc[1][n] = __builtin_amdgcn_mfma_f32_16x16x32_f16(a1, b, acc[1][n], 0, 0, 0);
      }
    }
  }
#pragma unroll
  for (int n = 0; n < 4; ++n) {
    int col = wc * 64 + n * 16 + (lane & 15);
    float bn = bias[col];
#pragma unroll
    for (int m = 0; m < 2; ++m) {
#pragma unroll
      for (int r = 0; r < 4; ++r) {
        float v = fmaxf(acc[m][n][r] + bn, 0.0f);
        lds_st1(Obuf, wr * 32 + m * 16 + (lane >> 4) * 4 + r, col, f2h(v));
      }
    }
  }
}

__global__ __launch_bounds__(256) void janossy_kernel(
    const float* __restrict__ h, const int* __restrict__ idx0,
    const int* __restrict__ idx1, const int* __restrict__ idx2,
    const int* __restrict__ idx3, const float* __restrict__ b1,
    const float* __restrict__ b2, const float* __restrict__ b3,
    const float* __restrict__ bo, const unsigned short* __restrict__ P,
    float* __restrict__ out) {
  __shared__ __attribute__((aligned(16))) unsigned short sA[64 * 128];
  __shared__ __attribute__((aligned(16))) unsigned short tA[64 * 128];
  __shared__ __attribute__((aligned(16))) unsigned short xA[64 * 128];
  const int tid = threadIdx.x;
  const int lane = tid & 63;
  const int wid = tid >> 6;
  const int wr = wid & 1, wc = wid >> 1;
  const int blk = blockIdx.x;
  {
    int row = tid >> 2, q = tid & 3;
    int rg = blk * 64 + row;
    if (rg < N_IMP) {
      const float4* p0 = (const float4*)h + (long)idx0[rg] * 32 + q * 8;
      const float4* p1 = (const float4*)h + (long)idx1[rg] * 32 + q * 8;
      const float4* p2 = (const float4*)h + (long)idx2[rg] * 32 + q * 8;
      const float4* p3 = (const float4*)h + (long)idx3[rg] * 32 + q * 8;
#pragma unroll
      for (int c = 0; c < 8; ++c) {
        float4 v0 = p0[c], v1 = p1[c], v2 = p2[c], v3 = p3[c];
        int k0 = q * 32 + c * 4;
        lds_st4(sA, row, k0, v0.x + v2.x + v3.x, v0.y + v2.y + v3.y,
                v0.z + v2.z + v3.z, v0.w + v2.w + v3.w);
        lds_st4(tA, row, k0, v1.x, v1.y, v1.z, v1.w);
      }
    } else {
#pragma unroll
      for (int c = 0; c < 8; ++c) {
        int k0 = q * 32 + c * 4;
        lds_st4(sA, row, k0, 0.f, 0.f, 0.f, 0.f);
        lds_st4(tA, row, k0, 0.f, 0.f, 0.f, 0.f);
      }
    }
  }
  __syncthreads();
  mlp_layer<true>(sA, P, tA, P + 16384, b1, xA, lane, wr, wc);
  __syncthreads();
  mlp_layer<false>(xA, P + 32768, nullptr, nullptr, b2, sA, lane, wr, wc);
  __syncthreads();
  mlp_layer<false>(sA, P + 49152, nullptr, nullptr, b3, tA, lane, wr, wc);
  __syncthreads();
  {
    f32x4 acc = {0.f, 0.f, 0.f, 0.f};
#pragma unroll
    for (int ks = 0; ks < 4; ++ks) {
      int k0 = ks * 32 + (lane >> 4) * 8;
      f16x8 a = lds_frag(tA, wid * 16 + (lane & 15), k0);
      f16x8 b = *(const f16x8*)(P + 65536 + (lane & 15) * 128 + k0);
      acc = __builtin_amdgcn_mfma_f32_16x16x32_f16(a, b, acc, 0, 0, 0);
    }
    int col = lane & 15;
    if (col < 6) {
      float bov = bo[col];
#pragma unroll
      for (int r = 0; r < 4; ++r) {
        int rg = blk * 64 + wid * 16 + (lane >> 4) * 4 + r;
        if (rg < N_IMP) out[rg * 6 + col] = acc[r] + bov;
      }
    }
  }
}

extern "C" void kernel_launch(void* const* d_in, const int* in_sizes, int n_in,
                              void* d_out, int out_size, void* d_ws, size_t ws_size,
                              hipStream_t stream) {
  const float* h   = (const float*)d_in[0];
  const int* idx0  = (const int*)d_in[1];
  const int* idx1  = (const int*)d_in[2];
  const int* idx2  = (const int*)d_in[3];
  const int* idx3  = (const int*)d_in[4];
  const float* W1  = (const float*)d_in[5];
  const float* b1  = (const float*)d_in[6];
  const float* W2  = (const float*)d_in[7];
  const float* b2  = (const float*)d_in[8];
  const float* W3  = (const float*)d_in[9];
  const float* b3  = (const float*)d_in[10];
  const float* Wo  = (const float*)d_in[11];
  const float* bo  = (const float*)d_in[12];
  float* out = (float*)d_out;
  unsigned short* P = (unsigned short*)d_ws;

  prep_kernel<<<dim3(264), dim3(256), 0, stream>>>(W1, W2, W3, Wo, P);
  if (ws_size >= WS_NEED) {
    unsigned short* uv = P + UV_OFF;
    atom_gemm<<<dim3((N_ATOMS + 63) / 64), dim3(256), 0, stream>>>(h, P, uv);
    janossy2<<<dim3((N_IMP + 63) / 64), dim3(256), 0, stream>>>(
        uv, idx0, idx1, idx2, idx3, b1, b2, b3, bo, P, out);
  } else {
    janossy_kernel<<<dim3((N_IMP + 63) / 64), dim3(256), 0, stream>>>(
        h, idx0, idx1, idx2, idx3, b1, b2, b3, bo, P, out);
  }
}